// Round 15
// baseline (27.538 us; speedup 1.0000x reference)
//
#include <hip/hip_runtime.h>

// Problem constants (match reference setup_inputs)
#define MM 100000            // frames
#define CC 24                // cameras
#define BLK 256              // 4 waves per block
#define WPB (BLK / 64)       // waves per block
#define GRID 1280            // persistent blocks (5 per CU exactly)
#define NW (GRID * WPB)      // total waves = 5120
#define NP (MM / 2)          // frame-pairs = 50000 (each wave-iter does 2 frames)

// Element-count strides per iteration step (constant -> strength-reduced)
#define P2S (2 * NW * CC * 6)
#define P3S (2 * NW * 9)
#define MSS (2 * NW * CC)

// Per-(frame,camera) working set for one pipeline stage (kept in VGPRs).
struct Pack {
    float2 a0, a1, a2;   // observed pixels for 3 points
    float  w;            // mask weight (0 for idle lanes)
    float  q[9];         // pole3d of this half-wave's frame (broadcast loads)
};

// Loads via carried per-lane pointers (no per-iteration address re-derivation).
__device__ __forceinline__ Pack load_pack(
    const float* __restrict__ p2p, const float* __restrict__ p3p,
    const int* __restrict__ msp, float active)
{
    Pack pk;
    const float2* pd = (const float2*)p2p;
    pk.a0 = pd[0]; pk.a1 = pd[1]; pk.a2 = pd[2];
    pk.w  = active * (float)(*msp);
    #pragma unroll
    for (int i = 0; i < 9; ++i) pk.q[i] = p3p[i];   // same addr across half -> HW broadcast
    return pk;
}

// Read-pin: forces the prefetch loads to issue (and stay live in VGPRs) at
// this program point — the compiler cannot sink them past it (r10: VGPR=48
// proved sinking; r11: pin recovered it).
__device__ __forceinline__ void pin(const Pack& p) {
    asm volatile("" ::
        "v"(p.a0.x), "v"(p.a0.y), "v"(p.a1.x), "v"(p.a1.y),
        "v"(p.a2.x), "v"(p.a2.y), "v"(p.w),
        "v"(p.q[0]), "v"(p.q[1]), "v"(p.q[2]), "v"(p.q[3]), "v"(p.q[4]),
        "v"(p.q[5]), "v"(p.q[6]), "v"(p.q[7]), "v"(p.q[8]));
}

__global__ __launch_bounds__(BLK) void ba_main_kernel(
    const float* __restrict__ pole3d,   // [M,3,3]
    const float* __restrict__ pole2d,   // [M,C,3,2]
    const float* __restrict__ Kmat,     // [C,3,3]
    const float* __restrict__ dist,     // [C,5]
    const float* __restrict__ Rmat,     // [C,3,3]
    const float* __restrict__ tvec,     // [C,3]
    const int*   __restrict__ mask,     // [M,C]
    float* __restrict__ ws)             // [GRID] per-block partials
{
    const int tid  = threadIdx.x;
    const int lane = tid & 63;
    const int half = lane >> 5;               // which frame of the pair
    const int cl   = lane & 31;               // camera lane 0..31
    const int c    = (cl < CC) ? cl : (CC - 1);
    const float active = (cl < CC) ? 1.f : 0.f;

    // Per-lane camera parameters in registers (loaded once per block lifetime)
    const float fx = Kmat[c * 9 + 0], fy = Kmat[c * 9 + 4];
    const float u0 = Kmat[c * 9 + 2], v0 = Kmat[c * 9 + 5];
    const float k1 = dist[c * 5 + 0], k2 = dist[c * 5 + 1];
    const float p1 = dist[c * 5 + 2], p2 = dist[c * 5 + 3], k3 = dist[c * 5 + 4];
    const float r00 = Rmat[c * 9 + 0], r01 = Rmat[c * 9 + 1], r02 = Rmat[c * 9 + 2];
    const float r10 = Rmat[c * 9 + 3], r11 = Rmat[c * 9 + 4], r12 = Rmat[c * 9 + 5];
    const float r20 = Rmat[c * 9 + 6], r21 = Rmat[c * 9 + 7], r22 = Rmat[c * 9 + 8];
    const float t0 = tvec[c * 3 + 0], t1 = tvec[c * 3 + 1], t2 = tvec[c * 3 + 2];

    const int wid = blockIdx.x * WPB + (tid >> 6);   // global wave id

    // Carried per-lane pointers; advance by CONSTANT strides each iteration.
    const int m0 = 2 * wid + half;
    const float* p2p = pole2d + ((size_t)m0 * CC + c) * 6;
    const float* p3p = pole3d + (size_t)m0 * 9;
    const int*   msp = mask + (size_t)m0 * CC + c;

    float acc = 0.f;   // per-LANE partial: sum over frames of s_c*w_c/(3*wcnt_f)

    auto consume = [&](const Pack& pk) {
        float s = 0.f;
        #pragma unroll
        for (int i = 0; i < 3; ++i) {
            const float X = pk.q[3 * i + 0], Y = pk.q[3 * i + 1], Z = pk.q[3 * i + 2];
            const float xc = r00 * X + r01 * Y + r02 * Z + t0;
            const float yc = r10 * X + r11 * Y + r12 * Z + t1;
            const float zc = r20 * X + r21 * Y + r22 * Z + t2;
            const float inv = __builtin_amdgcn_rcpf(zc);
            const float x0 = xc * inv, x1 = yc * inv;
            const float r2 = x0 * x0 + x1 * x1;
            const float radial = 1.f + r2 * (k1 + r2 * (k2 + r2 * k3));
            const float xu = x0 * radial + 2.f * p1 * x0 * x1 + p2 * (r2 + 2.f * x0 * x0);
            const float yu = x1 * radial + p1 * (r2 + 2.f * x1 * x1) + 2.f * p2 * x0 * x1;
            const float uu = fx * xu + u0;
            const float vv = fy * yu + v0;
            const float dx = (i == 0 ? pk.a0.x : i == 1 ? pk.a1.x : pk.a2.x) - uu;
            const float dy = (i == 0 ? pk.a0.y : i == 1 ? pk.a1.y : pk.a2.y) - vv;
            s += __builtin_amdgcn_sqrtf(dx * dx + dy * dy);
        }
        // Frame's visible-camera count via ONE ballot (mask is 0/1); per-lane
        // accumulate — no cross-lane reduce inside the loop.
        const unsigned long long ball = __ballot(pk.w != 0.f);
        const unsigned wcnt = half ? __popcll(ball >> 32)
                                   : __popcll(ball & 0xFFFFFFFFull);
        acc += s * pk.w * __builtin_amdgcn_rcpf((float)(3u * wcnt));
    };

    // 2-deep software pipeline. Every wave has >=9 iterations (NP/NW = 9.77),
    // so the two prologue loads are always in range (wid + NW < NP for all wid).
    Pack c0 = load_pack(p2p, p3p, msp, active);
    pin(c0);
    Pack c1 = load_pack(p2p + P2S, p3p + P3S, msp + MSS, active);
    pin(c1);

    int p = wid;
    while (p + 2 * NW < NP) {
        Pack n = load_pack(p2p + 2 * P2S, p3p + 2 * P3S, msp + 2 * MSS, active);
        pin(n);
        consume(c0);
        c0 = c1; c1 = n;
        p2p += P2S; p3p += P3S; msp += MSS;
        p += NW;
    }
    consume(c0);                       // iteration p (always valid)
    if (p + NW < NP) consume(c1);      // iteration p+NW (wave-uniform guard)

    // Single 64-lane reduction AFTER the loop (sums cameras AND both halves)
    float tot = acc;
    #pragma unroll
    for (int d = 1; d < 64; d <<= 1) tot += __shfl_xor(tot, d);

    // One value per wave -> LDS -> one value per block
    __shared__ float sh[WPB];
    if (lane == 0) sh[tid >> 6] = tot;
    __syncthreads();
    if (tid == 0) {
        float bl = 0.f;
        #pragma unroll
        for (int j = 0; j < WPB; ++j) bl += sh[j];
        ws[blockIdx.x] = bl;
    }
}

__global__ __launch_bounds__(256) void ba_reduce_kernel(
    const float* __restrict__ ws, float* __restrict__ out)
{
    __shared__ float sh[256];
    float s = 0.f;
    for (int i = threadIdx.x; i < GRID; i += 256) s += ws[i];
    sh[threadIdx.x] = s;
    __syncthreads();
    #pragma unroll
    for (int st = 128; st > 0; st >>= 1) {
        if (threadIdx.x < st) sh[threadIdx.x] += sh[threadIdx.x + st];
        __syncthreads();
    }
    if (threadIdx.x == 0) out[0] = sh[0] * (1.0f / MM);
}

extern "C" void kernel_launch(void* const* d_in, const int* in_sizes, int n_in,
                              void* d_out, int out_size, void* d_ws, size_t ws_size,
                              hipStream_t stream) {
    const float* pole3d = (const float*)d_in[0];
    const float* pole2d = (const float*)d_in[1];
    const float* Kmat   = (const float*)d_in[2];
    const float* dist   = (const float*)d_in[3];
    const float* Rmat   = (const float*)d_in[4];
    const float* tvec   = (const float*)d_in[5];
    // d_in[6] = pole (unused: LINE_W = LENGTH_W = 0)
    const int*   mask   = (const int*)d_in[7];
    float* out = (float*)d_out;
    float* ws  = (float*)d_ws;   // GRID floats = 5 KB

    ba_main_kernel<<<GRID, BLK, 0, stream>>>(
        pole3d, pole2d, Kmat, dist, Rmat, tvec, mask, ws);
    ba_reduce_kernel<<<1, 256, 0, stream>>>(ws, out);
}

// Round 16
// 26.418 us; speedup vs baseline: 1.0424x; 1.0424x over previous
//
#include <hip/hip_runtime.h>

// Problem constants (match reference setup_inputs)
#define MM 100000            // frames
#define CC 24                // cameras
#define BLK 256              // 4 waves per block
#define WPB (BLK / 64)       // waves per block
#define GRID 1024            // 4 blocks/CU EXACTLY — one clean residency round
                             // (r10 occupancy 40% => effective cap ~4 blocks/CU;
                             //  GRID 1280 packed as 4+1 -> ~2x wall for the tail round)
#define NW (GRID * WPB)      // total waves = 4096
#define NP (MM / 2)          // frame-pairs = 50000 (each wave-iter does 2 frames)

// Element-count strides per iteration step (constant -> strength-reduced)
#define P2S (2 * NW * CC * 6)
#define P3S (2 * NW * 9)
#define MSS (2 * NW * CC)

// Per-(frame,camera) working set for one pipeline stage (kept in VGPRs).
struct Pack {
    float2 a0, a1, a2;   // observed pixels for 3 points
    float  w;            // mask weight (0 for idle lanes)
    float  q[9];         // pole3d of this half-wave's frame (broadcast loads)
};

// Loads via carried per-lane pointers (no per-iteration address re-derivation).
__device__ __forceinline__ Pack load_pack(
    const float* __restrict__ p2p, const float* __restrict__ p3p,
    const int* __restrict__ msp, float active)
{
    Pack pk;
    const float2* pd = (const float2*)p2p;
    pk.a0 = pd[0]; pk.a1 = pd[1]; pk.a2 = pd[2];
    pk.w  = active * (float)(*msp);
    #pragma unroll
    for (int i = 0; i < 9; ++i) pk.q[i] = p3p[i];   // same addr across half -> HW broadcast
    return pk;
}

// Read-pin: forces the prefetch loads to issue (and stay live in VGPRs) at
// this program point — the compiler cannot sink them past it (r10: VGPR=48
// proved sinking; r11: pin recovered it).
__device__ __forceinline__ void pin(const Pack& p) {
    asm volatile("" ::
        "v"(p.a0.x), "v"(p.a0.y), "v"(p.a1.x), "v"(p.a1.y),
        "v"(p.a2.x), "v"(p.a2.y), "v"(p.w),
        "v"(p.q[0]), "v"(p.q[1]), "v"(p.q[2]), "v"(p.q[3]), "v"(p.q[4]),
        "v"(p.q[5]), "v"(p.q[6]), "v"(p.q[7]), "v"(p.q[8]));
}

__global__ __launch_bounds__(BLK) void ba_main_kernel(
    const float* __restrict__ pole3d,   // [M,3,3]
    const float* __restrict__ pole2d,   // [M,C,3,2]
    const float* __restrict__ Kmat,     // [C,3,3]
    const float* __restrict__ dist,     // [C,5]
    const float* __restrict__ Rmat,     // [C,3,3]
    const float* __restrict__ tvec,     // [C,3]
    const int*   __restrict__ mask,     // [M,C]
    float* __restrict__ ws)             // [GRID] per-block partials
{
    const int tid  = threadIdx.x;
    const int lane = tid & 63;
    const int half = lane >> 5;               // which frame of the pair
    const int cl   = lane & 31;               // camera lane 0..31
    const int c    = (cl < CC) ? cl : (CC - 1);
    const float active = (cl < CC) ? 1.f : 0.f;

    // Per-lane camera parameters in registers (loaded once per block lifetime)
    const float fx = Kmat[c * 9 + 0], fy = Kmat[c * 9 + 4];
    const float u0 = Kmat[c * 9 + 2], v0 = Kmat[c * 9 + 5];
    const float k1 = dist[c * 5 + 0], k2 = dist[c * 5 + 1];
    const float p1 = dist[c * 5 + 2], p2 = dist[c * 5 + 3], k3 = dist[c * 5 + 4];
    const float r00 = Rmat[c * 9 + 0], r01 = Rmat[c * 9 + 1], r02 = Rmat[c * 9 + 2];
    const float r10 = Rmat[c * 9 + 3], r11 = Rmat[c * 9 + 4], r12 = Rmat[c * 9 + 5];
    const float r20 = Rmat[c * 9 + 6], r21 = Rmat[c * 9 + 7], r22 = Rmat[c * 9 + 8];
    const float t0 = tvec[c * 3 + 0], t1 = tvec[c * 3 + 1], t2 = tvec[c * 3 + 2];

    const int wid = blockIdx.x * WPB + (tid >> 6);   // global wave id

    // Carried per-lane pointers; advance by CONSTANT strides each iteration.
    const int m0 = 2 * wid + half;
    const float* p2p = pole2d + ((size_t)m0 * CC + c) * 6;
    const float* p3p = pole3d + (size_t)m0 * 9;
    const int*   msp = mask + (size_t)m0 * CC + c;

    float acc = 0.f;   // per-LANE partial: sum over frames of s_c*w_c/(3*wcnt_f)

    auto consume = [&](const Pack& pk) {
        float s = 0.f;
        #pragma unroll
        for (int i = 0; i < 3; ++i) {
            const float X = pk.q[3 * i + 0], Y = pk.q[3 * i + 1], Z = pk.q[3 * i + 2];
            const float xc = r00 * X + r01 * Y + r02 * Z + t0;
            const float yc = r10 * X + r11 * Y + r12 * Z + t1;
            const float zc = r20 * X + r21 * Y + r22 * Z + t2;
            const float inv = __builtin_amdgcn_rcpf(zc);
            const float x0 = xc * inv, x1 = yc * inv;
            const float r2 = x0 * x0 + x1 * x1;
            const float radial = 1.f + r2 * (k1 + r2 * (k2 + r2 * k3));
            const float xu = x0 * radial + 2.f * p1 * x0 * x1 + p2 * (r2 + 2.f * x0 * x0);
            const float yu = x1 * radial + p1 * (r2 + 2.f * x1 * x1) + 2.f * p2 * x0 * x1;
            const float uu = fx * xu + u0;
            const float vv = fy * yu + v0;
            const float dx = (i == 0 ? pk.a0.x : i == 1 ? pk.a1.x : pk.a2.x) - uu;
            const float dy = (i == 0 ? pk.a0.y : i == 1 ? pk.a1.y : pk.a2.y) - vv;
            s += __builtin_amdgcn_sqrtf(dx * dx + dy * dy);
        }
        // Frame's visible-camera count via ONE ballot (mask is 0/1); per-lane
        // accumulate — no cross-lane reduce inside the loop.
        const unsigned long long ball = __ballot(pk.w != 0.f);
        const unsigned wcnt = half ? __popcll(ball >> 32)
                                   : __popcll(ball & 0xFFFFFFFFull);
        acc += s * pk.w * __builtin_amdgcn_rcpf((float)(3u * wcnt));
    };

    // Prologue load; steady-state prefetches UNCONDITIONALLY at +stride
    // (guard is the loop bound, not a clamp); final iteration peeled.
    Pack cur = load_pack(p2p, p3p, msp, active);
    pin(cur);

    for (int p = wid; p + NW < NP; p += NW) {
        Pack nxt = load_pack(p2p + P2S, p3p + P3S, msp + MSS, active);
        pin(nxt);
        consume(cur);
        p2p += P2S; p3p += P3S; msp += MSS;
        cur = nxt;
    }
    consume(cur);   // peeled last iteration (no prefetch)

    // Single 64-lane reduction AFTER the loop (sums cameras AND both halves)
    float tot = acc;
    #pragma unroll
    for (int d = 1; d < 64; d <<= 1) tot += __shfl_xor(tot, d);

    // One value per wave -> LDS -> one value per block
    __shared__ float sh[WPB];
    if (lane == 0) sh[tid >> 6] = tot;
    __syncthreads();
    if (tid == 0) {
        float bl = 0.f;
        #pragma unroll
        for (int j = 0; j < WPB; ++j) bl += sh[j];
        ws[blockIdx.x] = bl;
    }
}

__global__ __launch_bounds__(256) void ba_reduce_kernel(
    const float* __restrict__ ws, float* __restrict__ out)
{
    __shared__ float sh[256];
    float s = 0.f;
    for (int i = threadIdx.x; i < GRID; i += 256) s += ws[i];
    sh[threadIdx.x] = s;
    __syncthreads();
    #pragma unroll
    for (int st = 128; st > 0; st >>= 1) {
        if (threadIdx.x < st) sh[threadIdx.x] += sh[threadIdx.x + st];
        __syncthreads();
    }
    if (threadIdx.x == 0) out[0] = sh[0] * (1.0f / MM);
}

extern "C" void kernel_launch(void* const* d_in, const int* in_sizes, int n_in,
                              void* d_out, int out_size, void* d_ws, size_t ws_size,
                              hipStream_t stream) {
    const float* pole3d = (const float*)d_in[0];
    const float* pole2d = (const float*)d_in[1];
    const float* Kmat   = (const float*)d_in[2];
    const float* dist   = (const float*)d_in[3];
    const float* Rmat   = (const float*)d_in[4];
    const float* tvec   = (const float*)d_in[5];
    // d_in[6] = pole (unused: LINE_W = LENGTH_W = 0)
    const int*   mask   = (const int*)d_in[7];
    float* out = (float*)d_out;
    float* ws  = (float*)d_ws;   // GRID floats = 4 KB

    ba_main_kernel<<<GRID, BLK, 0, stream>>>(
        pole3d, pole2d, Kmat, dist, Rmat, tvec, mask, ws);
    ba_reduce_kernel<<<1, 256, 0, stream>>>(ws, out);
}

// Round 17
// 23.297 us; speedup vs baseline: 1.1820x; 1.1340x over previous
//
#include <hip/hip_runtime.h>

// Problem constants (match reference setup_inputs)
#define MM 100000            // frames
#define CC 24                // cameras
#define BLK 256              // 4 waves per block
#define WPB (BLK / 64)       // waves per block
#define GRID 1024            // 4 blocks/CU (r16: == 1280 within noise; keep clean packing)
#define NW (GRID * WPB)      // total waves = 4096
#define NP (MM / 2)          // frame-pairs = 50000 (each wave-iter does 2 frames)

// Element-count strides per iteration step (constant -> strength-reduced)
#define P2S (2 * NW * CC * 6)
#define P3S (2 * NW * 9)
#define MSS (2 * NW * CC)

// Packed 2xf32 — clang ext_vector; arithmetic lowers to <2 x float> and the
// gfx950 backend selects V_PK_FMA_F32 / V_PK_MUL_F32 / V_PK_ADD_F32 (VOP3P),
// the only route to the chip's full FP32 rate (157 TF = 2x scalar).
typedef float f2 __attribute__((ext_vector_type(2)));

// Per-(frame,camera) working set for one pipeline stage (kept in VGPRs).
struct Pack {
    f2    a0, a1, a2;    // observed pixels for 3 points (naturally packed (x,y))
    float w;             // mask weight (0 for idle lanes)
    float q[9];          // pole3d of this half-wave's frame (broadcast loads)
};

// Loads via carried per-lane pointers (no per-iteration address re-derivation).
__device__ __forceinline__ Pack load_pack(
    const float* __restrict__ p2p, const float* __restrict__ p3p,
    const int* __restrict__ msp, float active)
{
    Pack pk;
    const f2* pd = (const f2*)p2p;      // 8B-aligned: (m*24+c)*24B offsets
    pk.a0 = pd[0]; pk.a1 = pd[1]; pk.a2 = pd[2];
    pk.w  = active * (float)(*msp);
    #pragma unroll
    for (int i = 0; i < 9; ++i) pk.q[i] = p3p[i];   // same addr across half -> HW broadcast
    return pk;
}

// Read-pin: forces the prefetch loads to issue (and stay live in VGPRs) at
// this program point — the compiler cannot sink them past it (r10: VGPR=48
// proved sinking; r11: pin recovered it).
__device__ __forceinline__ void pin(const Pack& p) {
    asm volatile("" ::
        "v"(p.a0.x), "v"(p.a0.y), "v"(p.a1.x), "v"(p.a1.y),
        "v"(p.a2.x), "v"(p.a2.y), "v"(p.w),
        "v"(p.q[0]), "v"(p.q[1]), "v"(p.q[2]), "v"(p.q[3]), "v"(p.q[4]),
        "v"(p.q[5]), "v"(p.q[6]), "v"(p.q[7]), "v"(p.q[8]));
}

__global__ __launch_bounds__(BLK) void ba_main_kernel(
    const float* __restrict__ pole3d,   // [M,3,3]
    const float* __restrict__ pole2d,   // [M,C,3,2]
    const float* __restrict__ Kmat,     // [C,3,3]
    const float* __restrict__ dist,     // [C,5]
    const float* __restrict__ Rmat,     // [C,3,3]
    const float* __restrict__ tvec,     // [C,3]
    const int*   __restrict__ mask,     // [M,C]
    float* __restrict__ ws)             // [GRID] per-block partials
{
    const int tid  = threadIdx.x;
    const int lane = tid & 63;
    const int half = lane >> 5;               // which frame of the pair
    const int cl   = lane & 31;               // camera lane 0..31
    const int c    = (cl < CC) ? cl : (CC - 1);
    const float active = (cl < CC) ? 1.f : 0.f;

    // Camera parameters — packed across the (x,y) channel where applicable.
    const float k1 = dist[c * 5 + 0], k2 = dist[c * 5 + 1], k3 = dist[c * 5 + 4];
    const float p1 = dist[c * 5 + 2], p2 = dist[c * 5 + 3];
    const f2 P12 = {p1, p2};                       // cross-term coeffs
    const f2 P21 = {p2, p1};                       // tangential coeffs (swapped)
    const f2 F   = {Kmat[c * 9 + 0], Kmat[c * 9 + 4]};   // (fx, fy)
    const f2 U0  = {Kmat[c * 9 + 2], Kmat[c * 9 + 5]};   // (u0, v0)
    const f2 RC0 = {Rmat[c * 9 + 0], Rmat[c * 9 + 3]};   // column 0 of rows 0,1
    const f2 RC1 = {Rmat[c * 9 + 1], Rmat[c * 9 + 4]};
    const f2 RC2 = {Rmat[c * 9 + 2], Rmat[c * 9 + 5]};
    const f2 T01 = {tvec[c * 3 + 0], tvec[c * 3 + 1]};
    const float r20 = Rmat[c * 9 + 6], r21 = Rmat[c * 9 + 7], r22 = Rmat[c * 9 + 8];
    const float t2  = tvec[c * 3 + 2];

    const int wid = blockIdx.x * WPB + (tid >> 6);   // global wave id

    // Carried per-lane pointers; advance by CONSTANT strides each iteration.
    const int m0 = 2 * wid + half;
    const float* p2p = pole2d + ((size_t)m0 * CC + c) * 6;
    const float* p3p = pole3d + (size_t)m0 * 9;
    const int*   msp = mask + (size_t)m0 * CC + c;

    float acc = 0.f;   // per-LANE partial: sum over frames of s_c*w_c/(3*wcnt_f)

    auto consume = [&](const Pack& pk) {
        float s = 0.f;
        const f2 obs[3] = {pk.a0, pk.a1, pk.a2};
        #pragma unroll
        for (int i = 0; i < 3; ++i) {
            const float X = pk.q[3 * i + 0], Y = pk.q[3 * i + 1], Z = pk.q[3 * i + 2];
            // Rows 0,1 of the rigid transform — packed (xc, yc)
            const f2 xy = RC0 * X + RC1 * Y + RC2 * Z + T01;
            const float zc = r20 * X + r21 * Y + r22 * Z + t2;
            const float inv = __builtin_amdgcn_rcpf(zc);
            const f2 V = xy * inv;                        // (x0, x1)
            const float r2v = V.x * V.x + V.y * V.y;
            const float radial = 1.f + r2v * (k1 + r2v * (k2 + r2v * k3));
            const float cross2 = 2.f * V.x * V.y;
            const f2 tang = r2v + 2.f * (V * V);          // (r2+2x0^2, r2+2x1^2)
            const f2 VU = V * radial + P12 * cross2 + P21 * tang;
            const f2 UV = F * VU + U0;
            const f2 d = obs[i] - UV;
            s += __builtin_amdgcn_sqrtf(d.x * d.x + d.y * d.y);
        }
        // Frame's visible-camera count via ONE ballot (mask is 0/1); per-lane
        // accumulate — no cross-lane reduce inside the loop.
        const unsigned long long ball = __ballot(pk.w != 0.f);
        const unsigned wcnt = half ? __popcll(ball >> 32)
                                   : __popcll(ball & 0xFFFFFFFFull);
        acc += s * pk.w * __builtin_amdgcn_rcpf((float)(3u * wcnt));
    };

    // Prologue load; steady-state prefetches UNCONDITIONALLY at +stride
    // (guard is the loop bound, not a clamp); final iteration peeled.
    Pack cur = load_pack(p2p, p3p, msp, active);
    pin(cur);

    for (int p = wid; p + NW < NP; p += NW) {
        Pack nxt = load_pack(p2p + P2S, p3p + P3S, msp + MSS, active);
        pin(nxt);
        consume(cur);
        p2p += P2S; p3p += P3S; msp += MSS;
        cur = nxt;
    }
    consume(cur);   // peeled last iteration (no prefetch)

    // Single 64-lane reduction AFTER the loop (sums cameras AND both halves)
    float tot = acc;
    #pragma unroll
    for (int d = 1; d < 64; d <<= 1) tot += __shfl_xor(tot, d);

    // One value per wave -> LDS -> one value per block
    __shared__ float sh[WPB];
    if (lane == 0) sh[tid >> 6] = tot;
    __syncthreads();
    if (tid == 0) {
        float bl = 0.f;
        #pragma unroll
        for (int j = 0; j < WPB; ++j) bl += sh[j];
        ws[blockIdx.x] = bl;
    }
}

__global__ __launch_bounds__(256) void ba_reduce_kernel(
    const float* __restrict__ ws, float* __restrict__ out)
{
    __shared__ float sh[256];
    float s = 0.f;
    for (int i = threadIdx.x; i < GRID; i += 256) s += ws[i];
    sh[threadIdx.x] = s;
    __syncthreads();
    #pragma unroll
    for (int st = 128; st > 0; st >>= 1) {
        if (threadIdx.x < st) sh[threadIdx.x] += sh[threadIdx.x + st];
        __syncthreads();
    }
    if (threadIdx.x == 0) out[0] = sh[0] * (1.0f / MM);
}

extern "C" void kernel_launch(void* const* d_in, const int* in_sizes, int n_in,
                              void* d_out, int out_size, void* d_ws, size_t ws_size,
                              hipStream_t stream) {
    const float* pole3d = (const float*)d_in[0];
    const float* pole2d = (const float*)d_in[1];
    const float* Kmat   = (const float*)d_in[2];
    const float* dist   = (const float*)d_in[3];
    const float* Rmat   = (const float*)d_in[4];
    const float* tvec   = (const float*)d_in[5];
    // d_in[6] = pole (unused: LINE_W = LENGTH_W = 0)
    const int*   mask   = (const int*)d_in[7];
    float* out = (float*)d_out;
    float* ws  = (float*)d_ws;   // GRID floats = 4 KB

    ba_main_kernel<<<GRID, BLK, 0, stream>>>(
        pole3d, pole2d, Kmat, dist, Rmat, tvec, mask, ws);
    ba_reduce_kernel<<<1, 256, 0, stream>>>(ws, out);
}